// Round 3
// baseline (380.747 us; speedup 1.0000x reference)
//
#include <hip/hip_runtime.h>
#include <stdint.h>

typedef unsigned int uint;
typedef unsigned short ushort;
typedef __attribute__((ext_vector_type(4))) float  f32x4;
typedef __attribute__((ext_vector_type(8))) __bf16 bf16x8;

#define SCALE 0.125f   // 1/sqrt(64)

__device__ __forceinline__ ushort f2bf(float f) {
  uint u = __builtin_bit_cast(uint, f);
  u += 0x7FFFu + ((u >> 16) & 1u);
  return (ushort)(u >> 16);
}
__device__ __forceinline__ uint pack2bf(float a, float b) {
  return (uint)f2bf(a) | ((uint)f2bf(b) << 16);
}
__device__ __forceinline__ float bflo(uint u) { return __builtin_bit_cast(float, u << 16); }
__device__ __forceinline__ float bfhi(uint u) { return __builtin_bit_cast(float, u & 0xFFFF0000u); }

__device__ __forceinline__ void gload_lds16(const void* g, void* l) {
  __builtin_amdgcn_global_load_lds((const __attribute__((address_space(1))) void*)g,
                                   (__attribute__((address_space(3))) void*)l, 16, 0, 0);
}

// ---------------- conversions ----------------

__global__ void cvt_x_kernel(const float4* __restrict__ in, uint2* __restrict__ out) {
  int i = blockIdx.x * blockDim.x + threadIdx.x;   // 524288 threads
  #pragma unroll
  for (int k = 0; k < 8; ++k) {
    int idx = i + k * 524288;                       // total 4194304 float4s
    float4 f = in[idx];
    out[idx] = make_uint2(pack2bf(f.x, f.y), pack2bf(f.z, f.w));
  }
}

// Wq/Wk/Wv [1024][1024] f32 -> WqkvT [3072][1024] bf16 (transposed: row=out col, k contiguous)
__global__ __launch_bounds__(256) void cvt_wqkv_kernel(
    const float* __restrict__ Wq, const float* __restrict__ Wk, const float* __restrict__ Wv,
    ushort* __restrict__ WT) {
  __shared__ float tile[32][33];
  int mat = blockIdx.z;
  const float* W = (mat == 0) ? Wq : (mat == 1) ? Wk : Wv;
  int tx = threadIdx.x & 31, ty = threadIdx.x >> 5;
  int c0 = blockIdx.x * 32, r0 = blockIdx.y * 32;
  #pragma unroll
  for (int i = 0; i < 4; ++i)
    tile[ty + i*8][tx] = W[(size_t)(r0 + ty + i*8) * 1024 + c0 + tx];
  __syncthreads();
  #pragma unroll
  for (int i = 0; i < 4; ++i)
    WT[(size_t)(mat*1024 + c0 + ty + i*8) * 1024 + r0 + tx] = f2bf(tile[tx][ty + i*8]);
}

// ---------------- 64-wide feature softmax helper (4 regs x 16 lanes, lg-group preserved) ----

__device__ __forceinline__ void fsoftmax4(float* v) {
  float mx = fmaxf(fmaxf(v[0], v[1]), fmaxf(v[2], v[3]));
  mx = fmaxf(mx, __shfl_xor(mx, 1));
  mx = fmaxf(mx, __shfl_xor(mx, 2));
  mx = fmaxf(mx, __shfl_xor(mx, 4));
  mx = fmaxf(mx, __shfl_xor(mx, 8));
  float s = 0.f;
  #pragma unroll
  for (int n = 0; n < 4; ++n) { v[n] = __expf((v[n] - mx) * SCALE); s += v[n]; }
  s += __shfl_xor(s, 1);
  s += __shfl_xor(s, 2);
  s += __shfl_xor(s, 4);
  s += __shfl_xor(s, 8);
  float inv = 1.f / s;
  #pragma unroll
  for (int n = 0; n < 4; ++n) v[n] *= inv;
}

// ---------------- bf16 GEMM, m97-style 128x128 tile, T1 XCD swizzle ----------------
// EPI=1: QKV GEMM; epilogue applies feature softmax: q-third -> qs, k-third (+mk softmax) -> wbuf,
//        v-third -> vbuf (all [16384][1024] bf16).
// EPI=0: plain float C = A@B^T + bias0 (GEMM2).
template<int EPI>
__global__ __launch_bounds__(256, 2) void gemm_bt(
    const ushort* __restrict__ A, const ushort* __restrict__ B, int K, int nbx,
    const float* __restrict__ bias0, const float* __restrict__ bias1, const float* __restrict__ bias2,
    const float* __restrict__ mk, ushort* __restrict__ qs, ushort* __restrict__ wbuf,
    ushort* __restrict__ vbuf, float* __restrict__ Cout, int ldc, int b_batch_stride) {
  __shared__ ushort As[128 * 64];
  __shared__ ushort Bs[128 * 64];
  const int t = threadIdx.x;
  const int w = t >> 6, l = t & 63;
  const int wr = w >> 1, wc = w & 1;

  // XCD-bijective swizzle (grid % 8 == 0)
  const int cpx = gridDim.x >> 3;
  const int bid = blockIdx.x;
  const int swz = (bid & 7) * cpx + (bid >> 3);
  const int m0 = (swz / nbx) * 128;
  const int n0 = (swz % nbx) * 128;

  const ushort* Ap = A + (size_t)m0 * K;
  const ushort* Bp = B + (size_t)(m0 >> 12) * b_batch_stride + (size_t)n0 * K;

  f32x4 acc[4][4];
  const f32x4 zf = {0.f, 0.f, 0.f, 0.f};
  #pragma unroll
  for (int i = 0; i < 4; ++i)
    #pragma unroll
    for (int j = 0; j < 4; ++j) acc[i][j] = zf;

  const int lr = l & 15, lg = l >> 4;

  for (int kt = 0; kt < K; kt += 64) {
    #pragma unroll
    for (int i = 0; i < 4; ++i) {
      int gb = w * 64 + i * 256;           // wave-uniform granule base
      int g  = gb + l;                     // per-lane granule
      int row = g >> 3, c16 = g & 7;
      gload_lds16(Ap + (size_t)row * K + kt + c16 * 8, (void*)(As + gb * 8));
      gload_lds16(Bp + (size_t)row * K + kt + c16 * 8, (void*)(Bs + gb * 8));
    }
    __syncthreads();
    #pragma unroll
    for (int kk = 0; kk < 64; kk += 32) {
      bf16x8 a[4], b[4];
      #pragma unroll
      for (int m = 0; m < 4; ++m)
        a[m] = *(const bf16x8*)(As + (wr*64 + m*16 + lr) * 64 + kk + lg * 8);
      #pragma unroll
      for (int n = 0; n < 4; ++n)
        b[n] = *(const bf16x8*)(Bs + (wc*64 + n*16 + lr) * 64 + kk + lg * 8);
      #pragma unroll
      for (int m = 0; m < 4; ++m)
        #pragma unroll
        for (int n = 0; n < 4; ++n)
          acc[m][n] = __builtin_amdgcn_mfma_f32_16x16x32_bf16(a[m], b[n], acc[m][n], 0, 0, 0);
    }
    __syncthreads();
  }

  // epilogue: C/D mapping col=lane&15, row=(lane>>4)*4+j (m89)
  if constexpr (EPI == 0) {
    #pragma unroll
    for (int n = 0; n < 4; ++n) {
      int col = n0 + wc*64 + n*16 + lr;
      float bv = bias0[col];
      #pragma unroll
      for (int m = 0; m < 4; ++m)
        #pragma unroll
        for (int j = 0; j < 4; ++j) {
          int row = m0 + wr*64 + m*16 + lg*4 + j;
          Cout[(size_t)row * ldc + col] = acc[m][n][j] + bv;
        }
    }
  } else {
    const int cwc = n0 + wc*64;           // global col base of this wave's 64-chunk
    if (n0 < 1024) {
      // q path: softmax(f32 acc + bq) -> qs
      #pragma unroll
      for (int m = 0; m < 4; ++m)
        #pragma unroll
        for (int j = 0; j < 4; ++j) {
          int row = m0 + wr*64 + m*16 + lg*4 + j;
          float v[4];
          #pragma unroll
          for (int n = 0; n < 4; ++n) v[n] = acc[m][n][j] + bias0[cwc + n*16 + lr];
          fsoftmax4(v);
          #pragma unroll
          for (int n = 0; n < 4; ++n)
            qs[(size_t)row * 1024 + cwc + n*16 + lr] = f2bf(v[n]);
        }
    } else if (n0 < 2048) {
      // k path: softmax(k) + softmax(mk) -> wbuf
      const int ck = cwc - 1024;
      #pragma unroll
      for (int m = 0; m < 4; ++m)
        #pragma unroll
        for (int j = 0; j < 4; ++j) {
          int row = m0 + wr*64 + m*16 + lg*4 + j;
          float v[4], mv[4];
          #pragma unroll
          for (int n = 0; n < 4; ++n) {
            v[n]  = acc[m][n][j] + bias1[ck + n*16 + lr];
            mv[n] = mk[(size_t)row * 1024 + ck + n*16 + lr];
          }
          fsoftmax4(v);
          fsoftmax4(mv);
          #pragma unroll
          for (int n = 0; n < 4; ++n)
            wbuf[(size_t)row * 1024 + ck + n*16 + lr] = f2bf(v[n] + mv[n]);
        }
    } else {
      // v path: plain bf16 store
      const int cv = cwc - 2048;
      #pragma unroll
      for (int n = 0; n < 4; ++n) {
        float bv = bias2[cv + n*16 + lr];
        #pragma unroll
        for (int m = 0; m < 4; ++m)
          #pragma unroll
          for (int j = 0; j < 4; ++j) {
            int row = m0 + wr*64 + m*16 + lg*4 + j;
            vbuf[(size_t)row * 1024 + cv + n*16 + lr] = f2bf(acc[m][n][j] + bv);
          }
      }
    }
  }
}

// ---------------- S[b,h] = (k_soft+m_soft)^T v : split-K outer-product + atomics ----------------

__global__ __launch_bounds__(256) void kv_accum_kernel(
    const ushort* __restrict__ wbuf, const ushort* __restrict__ vbuf, float* __restrict__ S) {
  __shared__ ushort Ws[128 * 64];
  __shared__ ushort Vs[128 * 64];
  int bx = blockIdx.x;
  int bh = bx >> 5, nc = bx & 31;
  int b = bh >> 4, h = bh & 15;
  int row0 = b * 4096 + nc * 128;
  int t = threadIdx.x, w = t >> 6, l = t & 63;
  #pragma unroll
  for (int i = 0; i < 4; ++i) {
    int gb = w * 64 + i * 256, g = gb + l;
    int r = g >> 3, c16 = g & 7;
    gload_lds16(wbuf + (size_t)(row0 + r) * 1024 + h * 64 + c16 * 8, (void*)(Ws + gb * 8));
    gload_lds16(vbuf + (size_t)(row0 + r) * 1024 + h * 64 + c16 * 8, (void*)(Vs + gb * 8));
  }
  __syncthreads();
  int d0 = (t & 15) * 4, e0 = (t >> 4) * 4;
  float acc[4][4] = {};
  #pragma unroll 4
  for (int n = 0; n < 128; ++n) {
    uint2 wp = *(const uint2*)(Ws + n * 64 + d0);
    uint2 vp = *(const uint2*)(Vs + n * 64 + e0);
    float wd[4] = { bflo(wp.x), bfhi(wp.x), bflo(wp.y), bfhi(wp.y) };
    float vd[4] = { bflo(vp.x), bfhi(vp.x), bflo(vp.y), bfhi(vp.y) };
    #pragma unroll
    for (int i = 0; i < 4; ++i)
      #pragma unroll
      for (int j = 0; j < 4; ++j) acc[i][j] += wd[i] * vd[j];
  }
  float* Sp = S + (size_t)bh * 4096;
  #pragma unroll
  for (int i = 0; i < 4; ++i)
    #pragma unroll
    for (int j = 0; j < 4; ++j)
      atomicAdd(Sp + (d0 + i) * 64 + e0 + j, acc[i][j]);
}

// ---------------- W2T[b][o][i] = sum_e S[b,h(i)][i%64][e] * Wo[h*64+e][o]  (bf16, BT layout) ----

__global__ __launch_bounds__(256) void make_w2t_kernel(
    const float* __restrict__ S, const float* __restrict__ Wo, ushort* __restrict__ W2T) {
  int bx = blockIdx.x;            // 1024 = b(4) h(16) ot(4) it(4)
  int b = bx >> 8, h = (bx >> 4) & 15, ot = (bx >> 2) & 3, it = bx & 3;
  int t = threadIdx.x;
  __shared__ float Ss[16 * 64];
  const float* Sp = S + (size_t)(b * 16 + h) * 4096 + it * 1024;
  #pragma unroll
  for (int i = 0; i < 4; ++i) Ss[t + i * 256] = Sp[t + i * 256];
  __syncthreads();
  int o = ot * 256 + t;
  float acc[16] = {};
  for (int e = 0; e < 64; ++e) {
    float wo = Wo[(size_t)(h * 64 + e) * 1024 + o];
    #pragma unroll
    for (int i = 0; i < 16; ++i) acc[i] += Ss[i * 64 + e] * wo;
  }
  ushort* dst = W2T + (size_t)(b * 1024 + o) * 1024 + h * 64 + it * 16;
  #pragma unroll
  for (int i = 0; i < 16; ++i) dst[i] = f2bf(acc[i]);
}

// ---------------- launch ----------------

extern "C" void kernel_launch(void* const* d_in, const int* in_sizes, int n_in,
                              void* d_out, int out_size, void* d_ws, size_t ws_size,
                              hipStream_t stream) {
  const float* x  = (const float*)d_in[0];
  const float* mk = (const float*)d_in[1];
  const float* Wq = (const float*)d_in[2];
  const float* bq = (const float*)d_in[3];
  const float* Wk = (const float*)d_in[4];
  const float* bk = (const float*)d_in[5];
  const float* Wv = (const float*)d_in[6];
  const float* bv = (const float*)d_in[7];
  const float* Wo = (const float*)d_in[8];
  const float* bo = (const float*)d_in[9];
  float* out = (float*)d_out;

  char* ws = (char*)d_ws;
  ushort* xb    = (ushort*)(ws);                    //  33,554,432
  ushort* wqkvT = (ushort*)(ws +  33554432);        //   6,291,456
  ushort* qs    = (ushort*)(ws +  39845888);        //  33,554,432
  ushort* wbuf  = (ushort*)(ws +  73400320);        //  33,554,432
  ushort* vbuf  = (ushort*)(ws + 106954752);        //  33,554,432
  float*  S     = (float* )(ws + 140509184);        //   1,048,576
  ushort* W2T   = (ushort*)(ws + 141557760);        //   8,388,608

  cvt_x_kernel<<<2048, 256, 0, stream>>>((const float4*)x, (uint2*)xb);
  cvt_wqkv_kernel<<<dim3(32, 32, 3), 256, 0, stream>>>(Wq, Wk, Wv, wqkvT);
  // GEMM1 + fused feature-softmax epilogue (q->qs, k+m->wbuf, v->vbuf)
  gemm_bt<1><<<3072, 256, 0, stream>>>(xb, wqkvT, 1024, 24, bq, bk, bv,
                                       mk, qs, wbuf, vbuf, nullptr, 0, 0);
  hipMemsetAsync(S, 0, 64 * 4096 * sizeof(float), stream);
  kv_accum_kernel<<<2048, 256, 0, stream>>>(wbuf, vbuf, S);
  make_w2t_kernel<<<1024, 256, 0, stream>>>(S, Wo, W2T);
  gemm_bt<0><<<1024, 256, 0, stream>>>(qs, W2T, 1024, 8, bo, nullptr, nullptr,
                                       nullptr, nullptr, nullptr, nullptr, out, 1024, 1024 * 1024);
}